// Round 10
// baseline (38.166 us; speedup 1.0000x reference)
//
#include <hip/hip_runtime.h>
#include <hip/hip_bf16.h>

typedef __attribute__((ext_vector_type(8))) short bf16x8;
typedef __attribute__((ext_vector_type(4))) float f32x4;
typedef __attribute__((ext_vector_type(16))) float f32x16;
typedef __attribute__((ext_vector_type(2))) unsigned int u32x2;
typedef unsigned short u16;
typedef unsigned int u32;

#define EMB 128

// round-to-nearest-even fp32 -> bf16
static __device__ __forceinline__ u16 f2bf(float f) {
    union { float f; u32 u; } v; v.f = f;
    u32 u = v.u;
    return (u16)((u + 0x7FFFu + ((u >> 16) & 1u)) >> 16);
}

static __device__ __forceinline__ u32 cvtpk(float a, float b) {
    u32 r;
    asm("v_cvt_pk_bf16_f32 %0, %1, %2" : "=v"(r) : "v"(a), "v"(b));
    return r;
}

// exchange: a' = [a.lo32 | b.lo32(partner)], b' = [a.hi32(partner) | b.hi32]
static __device__ __forceinline__ void plswap(u32& a, u32& b) {
#if __has_builtin(__builtin_amdgcn_permlane32_swap)
    u32x2 r = __builtin_amdgcn_permlane32_swap(a, b, false, false);
    a = r[0]; b = r[1];
#else
    u32 sa = __shfl_xor(a, 32), sb = __shfl_xor(b, 32);
    bool hi = (threadIdx.x & 32) != 0;
    u32 na = hi ? sb : a;
    u32 nb = hi ? b : sa;
    a = na; b = nb;
#endif
}

// Half-P-transform (verified in the PV path): 8 f32 regs of a 32x32 D tile
// (rows (r&3)+8*(r>>2)+4*hi2 = 0..15) + bias, scale -> bf16x8 fragment with
// (lane = col, element e = row hi2*8+e). Used to build qf/kf in-register.
static __device__ __forceinline__ bf16x8 half_xform(const f32x16& d,
        float4 bA, float4 bB, float scale) {
    u32 x0 = cvtpk((d[0] + bA.x) * scale, (d[1] + bA.y) * scale);
    u32 x1 = cvtpk((d[2] + bA.z) * scale, (d[3] + bA.w) * scale);
    u32 y0 = cvtpk((d[4] + bB.x) * scale, (d[5] + bB.y) * scale);
    u32 y1 = cvtpk((d[6] + bB.z) * scale, (d[7] + bB.w) * scale);
    plswap(x0, y0);
    plswap(x1, y1);
    union { u32 w[4]; bf16x8 v; } r;
    r.w[0] = x0; r.w[1] = x1; r.w[2] = y0; r.w[3] = y1;
    return r.v;
}

// ---------------------------------------------------------------------------
// Weight prep: wt[mat][n][k] = bf16(w[mat][k][n]), mat: q,k,v,o
__global__ void __launch_bounds__(256) k_prep(const float* __restrict__ wq,
        const float* __restrict__ wk, const float* __restrict__ wv,
        const float* __restrict__ wo, u16* __restrict__ wt) {
    int i = blockIdx.x * 256 + threadIdx.x;
    int mat = i >> 14, rem = i & 16383;
    int k = rem >> 7, n = rem & 127;
    const float* src = mat == 0 ? wq : mat == 1 ? wk : mat == 2 ? wv : wo;
    wt[mat * 16384 + n * 128 + k] = f2bf(src[rem]);
}

// ---------------------------------------------------------------------------
// Fused LN -> QKV -> attention -> out-proj. Block = (seq row, q-half):
// 512 blocks, 512 threads = 8 waves = 8 heads. Each block: full LN + full
// K/V (redundant across the 2 halves), own 64 q-tokens' attention + out-proj.
// Q/K never touch LDS: produced as register fragments via dup-head 32x32
// MFMA + half-P-transform. LDS (68 KB -> 2 blocks/CU):
//   [0,     34816)  Xs : LN'd X, [128 tok][136 u16]  (reused as ctxs, 64 rows)
//   [34816, 69632)  Vs : [8 h][16 d][136 tok-pitch] u16
__global__ void __launch_bounds__(512, 4) k_fused(const float* __restrict__ pe,
        const float* __restrict__ g, const float* __restrict__ bia,
        const u16* __restrict__ wt,
        const float* __restrict__ bq, const float* __restrict__ bk,
        const float* __restrict__ bv, const float* __restrict__ bo,
        const float* __restrict__ mask, float* __restrict__ out) {
    __shared__ __align__(16) char smem[69632];
    u16* Xs = reinterpret_cast<u16*>(smem);            // pitch 136
    u16* Vs = reinterpret_cast<u16*>(smem + 34816);
    char* ctxs = smem;                                  // 256B-pitch, swizzled

    int tid = threadIdx.x;
    int bx = blockIdx.x;
    int seq = bx >> 1, qh = bx & 1;
    int lane = tid & 63, h = tid >> 6;
    int lo = lane & 15, hi4 = lane >> 4;
    int lo2 = lane & 31, hi2 = lane >> 5;

    // ---- Phase 1: LayerNorm, 4 threads/token, 128 tokens (r9 verbatim) ----
    {
        int tl = tid >> 2;
        int q = tid & 3;
        const float4* src = reinterpret_cast<const float4*>(pe + (size_t)(seq * 128 + tl) * EMB);
        float4 v[8];
        float s = 0.f, ss = 0.f;
#pragma unroll
        for (int i = 0; i < 8; ++i) {
            v[i] = src[i * 4 + q];
            s += v[i].x + v[i].y + v[i].z + v[i].w;
            ss += v[i].x * v[i].x + v[i].y * v[i].y + v[i].z * v[i].z + v[i].w * v[i].w;
        }
        s += __shfl_xor(s, 1); ss += __shfl_xor(ss, 1);
        s += __shfl_xor(s, 2); ss += __shfl_xor(ss, 2);
        float mean = s * (1.f / EMB);
        float var = ss * (1.f / EMB) - mean * mean;
        float rstd = rsqrtf(var + 1e-5f);
#pragma unroll
        for (int i = 0; i < 8; ++i) {
            int c = i * 16 + q * 4;
            float4 gg = *reinterpret_cast<const float4*>(g + c);
            float4 bb = *reinterpret_cast<const float4*>(bia + c);
            uint2 packed;
            packed.x = (u32)f2bf((v[i].x - mean) * rstd * gg.x + bb.x)
                     | ((u32)f2bf((v[i].y - mean) * rstd * gg.y + bb.y) << 16);
            packed.y = (u32)f2bf((v[i].z - mean) * rstd * gg.z + bb.z)
                     | ((u32)f2bf((v[i].w - mean) * rstd * gg.w + bb.w) << 16);
            *reinterpret_cast<uint2*>(&Xs[tl * 136 + c]) = packed;
        }
    }
    __syncthreads();

    // ---- Phase 2a: V (16x16 normal order, r9 verbatim) -> Vs ----
    {
        bf16x8 bfv[4];
#pragma unroll
        for (int kk = 0; kk < 4; ++kk)
            bfv[kk] = *reinterpret_cast<const bf16x8*>(
                wt + 2 * 16384 + (h * 16 + lo) * 128 + kk * 32 + hi4 * 8);
        float bv_ = bv[h * 16 + lo];
#pragma unroll
        for (int sub = 0; sub < 8; ++sub) {
            f32x4 av = {};
#pragma unroll
            for (int kk = 0; kk < 4; ++kk) {
                bf16x8 a = *reinterpret_cast<const bf16x8*>(
                    &Xs[(sub * 16 + lo) * 136 + kk * 32 + hi4 * 8]);
                av = __builtin_amdgcn_mfma_f32_16x16x32_bf16(a, bfv[kk], av, 0, 0, 0);
            }
            int tokv = sub * 16 + hi4 * 4;
            uint2 pv;
            pv.x = (u32)f2bf(av[0] + bv_) | ((u32)f2bf(av[1] + bv_) << 16);
            pv.y = (u32)f2bf(av[2] + bv_) | ((u32)f2bf(av[3] + bv_) << 16);
            *reinterpret_cast<uint2*>(&Vs[h * 2176 + lo * 136 + tokv]) = pv;
        }
    }

    // ---- Phase 2b: K -> kf[4] register fragments (dup-head 32x32) ----
    bf16x8 kf[4], qf[2];
    {
        float4 bA = *reinterpret_cast<const float4*>(bk + h * 16 + hi2 * 4);
        float4 bB = *reinterpret_cast<const float4*>(bk + h * 16 + 8 + hi2 * 4);
        bf16x8 wf[8];
#pragma unroll
        for (int kk = 0; kk < 8; ++kk)
            wf[kk] = *reinterpret_cast<const bf16x8*>(
                wt + 1 * 16384 + (h * 16 + lo) * 128 + kk * 16 + hi2 * 8);
#pragma unroll
        for (int t = 0; t < 4; ++t) {
            f32x16 acc = {};
#pragma unroll
            for (int kk = 0; kk < 8; ++kk) {
                bf16x8 xf = *reinterpret_cast<const bf16x8*>(
                    &Xs[(t * 32 + lo2) * 136 + kk * 16 + hi2 * 8]);
                acc = __builtin_amdgcn_mfma_f32_32x32x16_bf16(wf[kk], xf, acc, 0, 0, 0);
            }
            kf[t] = half_xform(acc, bA, bB, 1.0f);
        }
    }
    // ---- Phase 2c: Q -> qf[2] (own q-half only) ----
    {
        float4 bA = *reinterpret_cast<const float4*>(bq + h * 16 + hi2 * 4);
        float4 bB = *reinterpret_cast<const float4*>(bq + h * 16 + 8 + hi2 * 4);
        bf16x8 wf[8];
#pragma unroll
        for (int kk = 0; kk < 8; ++kk)
            wf[kk] = *reinterpret_cast<const bf16x8*>(
                wt + 0 * 16384 + (h * 16 + lo) * 128 + kk * 16 + hi2 * 8);
#pragma unroll
        for (int ql = 0; ql < 2; ++ql) {
            int t = qh * 2 + ql;
            f32x16 acc = {};
#pragma unroll
            for (int kk = 0; kk < 8; ++kk) {
                bf16x8 xf = *reinterpret_cast<const bf16x8*>(
                    &Xs[(t * 32 + lo2) * 136 + kk * 16 + hi2 * 8]);
                acc = __builtin_amdgcn_mfma_f32_32x32x16_bf16(wf[kk], xf, acc, 0, 0, 0);
            }
            qf[ql] = half_xform(acc, bA, bB, 0.25f);
        }
    }
    __syncthreads();   // Xs dead for all waves -> reuse as ctxs; Vs ordered

    // ---- Phase 3: attention (kf/qf in regs, V from LDS), 2 q-tiles ----
    const f32x16 zero = {};
#pragma unroll
    for (int ql = 0; ql < 2; ++ql) {
        f32x16 s[4];
#pragma unroll
        for (int t = 0; t < 4; ++t)
            s[t] = __builtin_amdgcn_mfma_f32_32x32x16_bf16(kf[t], qf[ql], zero, 0, 0, 0);

        float m = s[0][0];
#pragma unroll
        for (int t = 0; t < 4; ++t)
#pragma unroll
            for (int r = 0; r < 16; ++r) m = fmaxf(m, s[t][r]);
        m = fmaxf(m, __shfl_xor(m, 32));

        float sum = 0.f;
        bf16x8 pb[8];
#pragma unroll
        for (int t = 0; t < 4; ++t) {
#pragma unroll
            for (int r = 0; r < 16; ++r) {
                float p = __expf(s[t][r] - m);
                s[t][r] = p;
                sum += p;
            }
#pragma unroll
            for (int half = 0; half < 2; ++half) {
                int hf = half * 8;
                u32 x0 = cvtpk(s[t][hf + 0], s[t][hf + 1]);
                u32 x1 = cvtpk(s[t][hf + 2], s[t][hf + 3]);
                u32 y0 = cvtpk(s[t][hf + 4], s[t][hf + 5]);
                u32 y1 = cvtpk(s[t][hf + 6], s[t][hf + 7]);
                plswap(x0, y0);
                plswap(x1, y1);
                union { u32 wd[4]; bf16x8 v; } pbu;
                pbu.wd[0] = x0; pbu.wd[1] = x1; pbu.wd[2] = y0; pbu.wd[3] = y1;
                pb[t * 2 + half] = pbu.v;
            }
        }
        sum += __shfl_xor(sum, 32);
        float inv = 1.f / sum;

        f32x16 o = {};
#pragma unroll
        for (int c = 0; c < 8; ++c) {
            bf16x8 va = *reinterpret_cast<const bf16x8*>(
                &Vs[h * 2176 + lo * 136 + c * 16 + hi2 * 8]);
            o = __builtin_amdgcn_mfma_f32_32x32x16_bf16(va, pb[c], o, 0, 0, 0);
        }

        int tok = ql * 32 + lo2;   // local token row 0..63
        u32 off0 = (u32)(tok * 256 + h * 32 + 8 * hi2) ^ ((tok & 7) << 4);
        u32 off1 = (u32)(tok * 256 + h * 32 + 16 + 8 * hi2) ^ ((tok & 7) << 4);
        uint2 p0, p1;
        p0.x = (u32)f2bf(o[0] * inv) | ((u32)f2bf(o[1] * inv) << 16);
        p0.y = (u32)f2bf(o[2] * inv) | ((u32)f2bf(o[3] * inv) << 16);
        p1.x = (u32)f2bf(o[4] * inv) | ((u32)f2bf(o[5] * inv) << 16);
        p1.y = (u32)f2bf(o[6] * inv) | ((u32)f2bf(o[7] * inv) << 16);
        *reinterpret_cast<uint2*>(ctxs + off0) = p0;
        *reinterpret_cast<uint2*>(ctxs + off1) = p1;
    }
    __syncthreads();

    // ---- Phase 4: out-proj for own 64 tokens. Wave w: token group w>>1,
    //      column half w&1 (64 cols). ----
    {
        int grp = h >> 1, ch = h & 1;
        const u16* wo = wt + 3 * 16384;
        f32x4 acc[4];
#pragma unroll
        for (int c = 0; c < 4; ++c) acc[c] = f32x4{0.f, 0.f, 0.f, 0.f};
#pragma unroll
        for (int kk = 0; kk < 4; ++kk) {
            int tokrow = grp * 16 + lo;
            u32 aoff = (u32)(tokrow * 256 + kk * 64 + hi4 * 16) ^ ((tokrow & 7) << 4);
            bf16x8 a = *reinterpret_cast<const bf16x8*>(ctxs + aoff);
#pragma unroll
            for (int c = 0; c < 4; ++c) {
                bf16x8 b = *reinterpret_cast<const bf16x8*>(
                    wo + (ch * 64 + c * 16 + lo) * 128 + kk * 32 + hi4 * 8);
                acc[c] = __builtin_amdgcn_mfma_f32_16x16x32_bf16(a, b, acc[c], 0, 0, 0);
            }
        }
#pragma unroll
        for (int c = 0; c < 4; ++c) {
            int col = ch * 64 + c * 16 + lo;
            float bval = bo[col];
#pragma unroll
            for (int j = 0; j < 4; ++j) {
                int t = seq * 128 + qh * 64 + grp * 16 + hi4 * 4 + j;
                out[(size_t)t * EMB + col] = (acc[c][j] + bval) * mask[t];
            }
        }
    }
}

// ---------------------------------------------------------------------------
extern "C" void kernel_launch(void* const* d_in, const int* in_sizes, int n_in,
                              void* d_out, int out_size, void* d_ws, size_t ws_size,
                              hipStream_t stream) {
    const float* pe   = (const float*)d_in[0];
    const float* mask = (const float*)d_in[1];
    const float* ln_g = (const float*)d_in[2];
    const float* ln_b = (const float*)d_in[3];
    const float* wq   = (const float*)d_in[4];
    const float* bq   = (const float*)d_in[5];
    const float* wk   = (const float*)d_in[6];
    const float* bk   = (const float*)d_in[7];
    const float* wv   = (const float*)d_in[8];
    const float* bv   = (const float*)d_in[9];
    const float* wo   = (const float*)d_in[10];
    const float* bo   = (const float*)d_in[11];
    float* out = (float*)d_out;

    u16* wt = (u16*)d_ws;            // 4 x [n][k] bf16 = 128 KB

    hipLaunchKernelGGL(k_prep,  dim3(256), dim3(256), 0, stream, wq, wk, wv, wo, wt);
    hipLaunchKernelGGL(k_fused, dim3(512), dim3(512), 0, stream, pe, ln_g, ln_b, wt,
                       bq, bk, bv, bo, mask, out);
}